// Round 3
// baseline (32361.526 us; speedup 1.0000x reference)
//
#include <hip/hip_runtime.h>
#include <stdint.h>

// ---------------------------------------------------------------------------
// BiLSTM encoder, persistent MFMA kernel (Round 3).
// 256 blocks x 256 threads, 1 block/CU. Groups: g0 fwd-L0 | g1 fwd-L1 |
// g2 bwd-L0 | g3 bwd-L1. L1 trails L0 by TWO epochs (4-slot ring) so its
// input half is barrier-independent.
// Waves per block: (batch-half bh, k-half kh). kh=0 waves compute the
// x/ring half BEFORE the grid-wait; kh=1 waves wait on `go` then compute
// the h half. A-fragments load straight from global (h/ring kept as
// separate hi/lo bf16 arrays -> no conversion). B-hi in registers (128
// VGPR), B-lo in LDS (XOR-swizzled). Split-bf16 3-product MFMA.
// Barrier: per-block flag stores, one aggregator per direction, single
// `go` word polled by kh=1 waves only.
// ---------------------------------------------------------------------------

#define B_ 32
#define T_ 1024
#define H_ 512
#define BH (B_ * H_)

typedef __attribute__((ext_vector_type(8))) short bf16x8;
typedef __attribute__((ext_vector_type(4))) float f32x4;

// ws byte layout
#define GO_OFF    0                       // go[dir] u32 at dir*128
#define FLAG_OFF  256                     // flags[2][128] u32
#define HHI_OFF   2048                    // [4 grp][2 buf][B][H] u16
#define HLO_OFF   (HHI_OFF + 262144)
#define C_OFF     (HLO_OFF + 262144)      // [4 grp][B][H] f32
#define RHI_OFF   (C_OFF + 262144)        // [2 dir][4 slot][B][H] u16
#define RLO_OFF   (RHI_OFF + 262144)
#define WS_BYTES  (RLO_OFF + 262144)      // ~1.0 MB

// LDS byte layout: WLO [0,64K) pitch 2048B/col, swz ((c&7)<<4).
// [64K,128K): temp WHI during init, then zb0/zb1 exchange buffers.
#define WHI_TMP   65536
#define ZB0_OFF   65536
#define ZB1_OFF   (65536 + 4352)
#define LDS_BYTES 131072

#define LOADU(p)  __hip_atomic_load((p), __ATOMIC_RELAXED, __HIP_MEMORY_SCOPE_AGENT)
#define STOREU(p, v) __hip_atomic_store((p), (v), __ATOMIC_RELAXED, __HIP_MEMORY_SCOPE_AGENT)

__device__ __forceinline__ float sigm(float x) { return 1.0f / (1.0f + __expf(-x)); }
__device__ __forceinline__ unsigned short bf16_rtn(float f) {
  unsigned u = __builtin_bit_cast(unsigned, f);
  unsigned r = u + 0x7FFFu + ((u >> 16) & 1u);
  return (unsigned short)(r >> 16);
}
__device__ __forceinline__ float bf16_to_f(unsigned short h) {
  return __builtin_bit_cast(float, (unsigned)h << 16);
}
__device__ __forceinline__ void split_f32(float f, unsigned short& hi, unsigned short& lo) {
  hi = bf16_rtn(f);
  lo = bf16_rtn(f - bf16_to_f(hi));
}

__global__ __launch_bounds__(256, 1)
void bilstm_v3(const float* __restrict__ inp, const int* __restrict__ lens,
               const float* __restrict__ Wf, const float* __restrict__ bfp,
               const float* __restrict__ Wb, const float* __restrict__ bbp,
               float* __restrict__ out, char* __restrict__ wsb) {
  extern __shared__ char lds[];
  const int tid = threadIdx.x, blk = blockIdx.x;
  const int group = blk >> 6, gslice = blk & 63;
  const int j0 = gslice * 8;
  const int dir = group >> 1, layer = group & 1;

  unsigned* gow   = (unsigned*)(wsb + GO_OFF) + dir * 32;
  unsigned* flags = (unsigned*)(wsb + FLAG_OFF) + dir * 128;
  unsigned short* hH = (unsigned short*)(wsb + HHI_OFF);
  unsigned short* hL = (unsigned short*)(wsb + HLO_OFF);
  float*          cg = (float*)(wsb + C_OFF) + group * BH;
  unsigned short* rH = (unsigned short*)(wsb + RHI_OFF) + dir * 4 * BH;
  unsigned short* rL = (unsigned short*)(wsb + RLO_OFF) + dir * 4 * BH;

  const float* Wg = (dir == 0 ? Wf : Wb) + (size_t)layer * 1024 * 2048;
  const float* bg = (dir == 0 ? bfp : bbp) + layer * 2048;

  // ---- init: stage W as bf16 hi->lds[WHI_TMP], lo->lds[0], swizzled ----
  for (int it = 0; it < 16; ++it) {
    int tt = tid + 256 * it;           // 4096 tasks = 1024 k x 4 gates
    int k = tt >> 2, gate = tt & 3;
    const float* src = Wg + (size_t)k * 2048 + gate * 512 + j0;
    float4 w0 = *(const float4*)src, w1 = *(const float4*)(src + 4);
    float wv[8] = {w0.x, w0.y, w0.z, w0.w, w1.x, w1.y, w1.z, w1.w};
#pragma unroll
    for (int u = 0; u < 8; ++u) {
      int c = u * 4 + gate;            // col = jj*4 + gate
      unsigned short hi, lo; split_f32(wv[u], hi, lo);
      int byte = c * 2048 + ((k * 2) ^ ((c & 7) << 4));
      *(unsigned short*)(lds + WHI_TMP + byte) = hi;
      *(unsigned short*)(lds + byte) = lo;
    }
  }
  __syncthreads();

  const int lane = tid & 63, wvid = tid >> 6;
  const int bh = wvid & 1, kh = wvid >> 1;   // batch-half, k-half
  const int fr = lane & 15, fq = lane >> 4;
  const int brow = bh * 16 + fr;             // batch row this lane loads

  // ---- B-hi fragments -> registers (128 VGPR) ----
  bf16x8 bhr[2][16];
#pragma unroll
  for (int nt = 0; nt < 2; ++nt) {
    const int colN = nt * 16 + fr;
    const char* base = lds + WHI_TMP + colN * 2048;
    const int xr = (colN & 7) << 4;
#pragma unroll
    for (int kk = 0; kk < 16; ++kk) {
      int off = ((kh * 512 + kk * 32 + fq * 8) * 2) ^ xr;
      bhr[nt][kk] = *(const bf16x8*)(base + off);
    }
  }
  __syncthreads();   // WHI_TMP region now free -> becomes zb0/zb1

  float* zb0 = (float*)(lds + ZB0_OFF);
  float* zb1 = (float*)(lds + ZB1_OFF);
  float* zbme = (kh == 0) ? zb0 : zb1;

  const int len_row = lens[brow];            // GEMM-lane length
  const int bi = tid >> 3, jj = tid & 7;     // pointwise mapping
  const int mylen = lens[bi];
  const float bias0 = bg[0 * 512 + j0 + jj];
  const float bias1 = bg[1 * 512 + j0 + jj];
  const float bias2 = bg[2 * 512 + j0 + jj];
  const float bias3 = bg[3 * 512 + j0 + jj];
  const int hidx = bi * H_ + j0 + jj;
  const bool isagg = (gslice == 0 && layer == 0);

  auto gemm_packed = [&](const unsigned short* ph, const unsigned short* pl,
                         f32x4 (&acc)[2][3]) {
    constexpr int PD = 6;
    bf16x8 rh[PD], rl[PD];
#pragma unroll
    for (int p = 0; p < PD; ++p) {
      rh[p] = *(const bf16x8*)(ph + p * 32);
      rl[p] = *(const bf16x8*)(pl + p * 32);
    }
#pragma unroll
    for (int kk = 0; kk < 16; ++kk) {
      bf16x8 ah = rh[kk % PD], al = rl[kk % PD];
      if (kk + PD < 16) {
        rh[kk % PD] = *(const bf16x8*)(ph + (kk + PD) * 32);
        rl[kk % PD] = *(const bf16x8*)(pl + (kk + PD) * 32);
      }
#pragma unroll
      for (int nt = 0; nt < 2; ++nt) {
        const int colN = nt * 16 + fr;
        int off = ((kh * 512 + kk * 32 + fq * 8) * 2) ^ ((colN & 7) << 4);
        bf16x8 bl = *(const bf16x8*)(lds + colN * 2048 + off);
        acc[nt][0] = __builtin_amdgcn_mfma_f32_16x16x32_bf16(ah, bhr[nt][kk], acc[nt][0], 0, 0, 0);
        acc[nt][1] = __builtin_amdgcn_mfma_f32_16x16x32_bf16(ah, bl,          acc[nt][1], 0, 0, 0);
        acc[nt][2] = __builtin_amdgcn_mfma_f32_16x16x32_bf16(al, bhr[nt][kk], acc[nt][2], 0, 0, 0);
      }
    }
  };

  auto gemm_f32 = [&](const float* xp, f32x4 (&acc)[2][3]) {
    constexpr int PD = 4;
    float4 ra[PD], rb[PD];
#pragma unroll
    for (int p = 0; p < PD; ++p) {
      ra[p] = *(const float4*)(xp + p * 32);
      rb[p] = *(const float4*)(xp + p * 32 + 4);
    }
#pragma unroll
    for (int kk = 0; kk < 16; ++kk) {
      float4 A = ra[kk % PD], Bv = rb[kk % PD];
      if (kk + PD < 16) {
        ra[kk % PD] = *(const float4*)(xp + (kk + PD) * 32);
        rb[kk % PD] = *(const float4*)(xp + (kk + PD) * 32 + 4);
      }
      float fv[8] = {A.x, A.y, A.z, A.w, Bv.x, Bv.y, Bv.z, Bv.w};
      bf16x8 ah, al;
#pragma unroll
      for (int i = 0; i < 8; ++i) {
        unsigned short h, l; split_f32(fv[i], h, l);
        ah[i] = (short)h; al[i] = (short)l;
      }
#pragma unroll
      for (int nt = 0; nt < 2; ++nt) {
        const int colN = nt * 16 + fr;
        int off = ((kk * 32 + fq * 8) * 2) ^ ((colN & 7) << 4);   // kh==0 here
        bf16x8 bl = *(const bf16x8*)(lds + colN * 2048 + off);
        acc[nt][0] = __builtin_amdgcn_mfma_f32_16x16x32_bf16(ah, bhr[nt][kk], acc[nt][0], 0, 0, 0);
        acc[nt][1] = __builtin_amdgcn_mfma_f32_16x16x32_bf16(ah, bl,          acc[nt][1], 0, 0, 0);
        acc[nt][2] = __builtin_amdgcn_mfma_f32_16x16x32_bf16(al, bhr[nt][kk], acc[nt][2], 0, 0, 0);
      }
    }
  };

#pragma unroll 1
  for (int s = 0; s <= 1025; ++s) {
    const bool act = layer ? (s >= 2) : (s < 1024);
    const int t = layer ? (s - 2) : s;
    if (act) {
      f32x4 acc[2][3] = {};
      if (kh == 0) {
        if (layer == 0) {
          int tr = t;
          if (dir == 1) tr = (t < len_row) ? (len_row - 1 - t) : t;
          const float* xp = inp + ((size_t)brow * T_ + tr) * 512 + fq * 8;
          gemm_f32(xp, acc);
        } else {
          // ring written 2 epochs ago; need go >= s-1 (also guards slot reuse)
          const unsigned tgt = (unsigned)(s - 1);
          while (LOADU(gow) < tgt) __builtin_amdgcn_s_sleep(1);
          __threadfence();
          const unsigned short* ph = rH + (t & 3) * BH + brow * 512 + fq * 8;
          const unsigned short* pl = rL + (t & 3) * BH + brow * 512 + fq * 8;
          gemm_packed(ph, pl, acc);
        }
      } else {
        // h half: wait for ALL blocks to finish epoch s-1
        const unsigned tgt = (unsigned)s;
        while (LOADU(gow) < tgt) __builtin_amdgcn_s_sleep(1);
        __threadfence();
        const unsigned short* ph = hH + (group * 2 + (s & 1)) * BH + brow * 512 + fq * 8;
        const unsigned short* pl = hL + (group * 2 + (s & 1)) * BH + brow * 512 + fq * 8;
        gemm_packed(ph, pl, acc);
      }
      // z partials -> LDS
#pragma unroll
      for (int nt = 0; nt < 2; ++nt) {
        f32x4 v = acc[nt][0] + acc[nt][1] + acc[nt][2];
#pragma unroll
        for (int r = 0; r < 4; ++r)
          zbme[(bh * 16 + fq * 4 + r) * 33 + nt * 16 + fr] = v[r];
      }
    }
    __syncthreads();
    if (act) {
      // pointwise LSTM cell: thread -> (batch bi, hidden j0+jj)
      const int zo_ = bi * 33 + jj * 4;
      float z0 = zb0[zo_ + 0] + zb1[zo_ + 0] + bias0;
      float z1 = zb0[zo_ + 1] + zb1[zo_ + 1] + bias1;
      float z2 = zb0[zo_ + 2] + zb1[zo_ + 2] + bias2;
      float z3 = zb0[zo_ + 3] + zb1[zo_ + 3] + bias3;
      float co = cg[hidx];
      float ig = sigm(z0), fgt = sigm(z2 + 1.0f), og = sigm(z3);
      float cn = fgt * co + ig * tanhf(z1);
      float hn = og * tanhf(cn);
      bool m = (t < mylen);
      const int rdoff = (group * 2 + (s & 1)) * BH + hidx;
      const int wroff = (group * 2 + ((s + 1) & 1)) * BH + hidx;
      unsigned short oh = hH[rdoff], ol = hL[rdoff];
      unsigned short nh, nl; split_f32(hn, nh, nl);
      cg[hidx] = m ? cn : co;
      hH[wroff] = m ? nh : oh;
      hL[wroff] = m ? nl : ol;
      if (layer == 0) {
        const int ro = (t & 3) * BH + hidx;
        rH[ro] = m ? nh : (unsigned short)0;
        rL[ro] = m ? nl : (unsigned short)0;
      } else {
        int ot = t;
        if (dir == 1) ot = (t < mylen) ? (mylen - 1 - t) : t;
        out[((size_t)bi * T_ + ot) * 1024 + dir * 512 + j0 + jj] = m ? hn : 0.0f;
      }
    }
    __syncthreads();
    if (tid == 0) {
      __threadfence();   // flush this block's epoch-s stores (wbl2)
      STOREU(&flags[layer * 64 + gslice], (unsigned)(s + 1));
    }
    if (isagg && wvid == 0 && s < 1025) {
      const unsigned tgt = (unsigned)(s + 1);
      while (true) {
        unsigned a = LOADU(&flags[lane]);
        unsigned b2 = LOADU(&flags[lane + 64]);
        if (__all(a >= tgt && b2 >= tgt)) break;
        __builtin_amdgcn_s_sleep(1);
      }
      if (lane == 0) {
        __threadfence();
        __hip_atomic_store(gow, tgt, __ATOMIC_RELEASE, __HIP_MEMORY_SCOPE_AGENT);
      }
    }
  }
}

extern "C" void kernel_launch(void* const* d_in, const int* in_sizes, int n_in,
                              void* d_out, int out_size, void* d_ws, size_t ws_size,
                              hipStream_t stream) {
  const float* inp   = (const float*)d_in[0];
  const int*   lensp = (const int*)d_in[1];
  const float* Wf    = (const float*)d_in[2];
  const float* bfp   = (const float*)d_in[3];
  const float* Wb    = (const float*)d_in[4];
  const float* bbp   = (const float*)d_in[5];
  float*       outp  = (float*)d_out;
  char*        wsp   = (char*)d_ws;
  (void)in_sizes; (void)n_in; (void)out_size; (void)ws_size;

  hipMemsetAsync(d_ws, 0, WS_BYTES, stream);
  hipFuncSetAttribute((const void*)bilstm_v3,
                      hipFuncAttributeMaxDynamicSharedMemorySize, LDS_BYTES);
  bilstm_v3<<<dim3(256), dim3(256), LDS_BYTES, stream>>>(
      inp, lensp, Wf, bfp, Wb, bbp, outp, wsp);
}

// Round 4
// 10713.573 us; speedup vs baseline: 3.0206x; 3.0206x over previous
//
#include <hip/hip_runtime.h>
#include <stdint.h>

// ---------------------------------------------------------------------------
// BiLSTM encoder, persistent MFMA kernel (Round 4).
// Key change vs R2/R3: NO __threadfence (no per-step L2 writeback). All
// cross-block data (h, ring y0, flags) uses agent-scope RELAXED ATOMIC u64
// accesses (write-through to coherence point; loads bypass stale L2).
// h/ring stored in MFMA fragment-major order: [rowgrp][kk][lane][2] u64,
// so consumer loads are lane-contiguous dwordx2. c/h-carry in registers.
// Step = phaseX (x/ring GEMM, no wait) -> flat flag poll -> phaseH (h GEMM,
// 4-deep prefetch) -> z LDS exchange -> pointwise -> fragment stores -> flag.
// ---------------------------------------------------------------------------

#define B_ 32
#define T_ 1024
#define H_ 512

typedef __attribute__((ext_vector_type(8))) short bf16x8;
typedef __attribute__((ext_vector_type(4))) float f32x4;
typedef __attribute__((ext_vector_type(4))) unsigned int u32x4;
typedef unsigned long long ull;
struct QQ { ull x, y; };

// ws byte layout
#define FLAG_OFF  0                     // flags[2 dir][128] u32
#define HH_OFF    4096                  // [4 grp][2 buf][4096] ull (h hi frags)
#define HL_OFF    (HH_OFF + 262144)     // h lo
#define RH_OFF    (HL_OFF + 262144)     // [2 dir][4 slot][4096] ull (ring hi)
#define RL_OFF    (RH_OFF + 262144)     // ring lo
#define WS_BYTES  (RL_OFF + 262144)     // ~1.03 MB

// LDS byte layout: B-lo [0,64K) u16 [32 col][1024 k] pitch 2048, swz ((c&7)<<4)
// [64K,128K): W-hi temp during init; then zb + staging buffers.
#define WHI_TMP   65536
#define ZB_OFF    65536                 // f32[32][33]
#define HS_OFF    (ZB_OFF + 4352)       // hstage: 128 ull (64 hi | 64 lo)
#define RS_OFF    (HS_OFF + 1024)       // rstage: 128 ull
#define LDS_BYTES 131072

#define LOADA(p)    __hip_atomic_load((p), __ATOMIC_RELAXED, __HIP_MEMORY_SCOPE_AGENT)
#define STOREA(p,v) __hip_atomic_store((p), (v), __ATOMIC_RELAXED, __HIP_MEMORY_SCOPE_AGENT)

__device__ __forceinline__ float sigm(float x) { return 1.f / (1.f + __expf(-x)); }
__device__ __forceinline__ unsigned short bf16_rtn(float f) {
  unsigned u = __builtin_bit_cast(unsigned, f);
  unsigned r = u + 0x7FFFu + ((u >> 16) & 1u);
  return (unsigned short)(r >> 16);
}
__device__ __forceinline__ float bf16f(unsigned short h) {
  return __builtin_bit_cast(float, (unsigned)h << 16);
}
__device__ __forceinline__ void split_f32(float f, unsigned short& hi, unsigned short& lo) {
  hi = bf16_rtn(f); lo = bf16_rtn(f - bf16f(hi));
}
// pack bf16(fa),bf16(fb) (truncating) into one u32 via v_perm
__device__ __forceinline__ unsigned packhi2(float fa, float fb) {
  return __builtin_amdgcn_perm(__builtin_bit_cast(unsigned, fb),
                               __builtin_bit_cast(unsigned, fa), 0x07060302u);
}
__device__ __forceinline__ float hipart(float f) {
  return __builtin_bit_cast(float, __builtin_bit_cast(unsigned, f) & 0xFFFF0000u);
}

#define MFMA3(AH, AL, BH, BLPTR) {                                            \
  bf16x8 bl_ = *(const bf16x8*)(BLPTR);                                       \
  acc0 = __builtin_amdgcn_mfma_f32_16x16x32_bf16((AH), (BH), acc0, 0, 0, 0);  \
  acc1 = __builtin_amdgcn_mfma_f32_16x16x32_bf16((AH), bl_,  acc1, 0, 0, 0);  \
  acc2 = __builtin_amdgcn_mfma_f32_16x16x32_bf16((AL), (BH), acc2, 0, 0, 0); }

// 16-fragment GEMM from agent-atomic u64 arrays, 4-deep register prefetch.
#define GEMM_FRAG(QH, QL, BHARR, BLBASE) {                                    \
  QQ rh[4], rl[4];                                                            \
  _Pragma("unroll")                                                           \
  for (int p = 0; p < 4; ++p) {                                               \
    const ull* ph_ = (QH) + ((size_t)p * 64 + lane) * 2;                      \
    const ull* pl_ = (QL) + ((size_t)p * 64 + lane) * 2;                      \
    rh[p].x = LOADA(ph_); rh[p].y = LOADA(ph_ + 1);                           \
    rl[p].x = LOADA(pl_); rl[p].y = LOADA(pl_ + 1);                           \
  }                                                                           \
  _Pragma("unroll")                                                           \
  for (int kk = 0; kk < 16; ++kk) {                                           \
    bf16x8 ah = __builtin_bit_cast(bf16x8, rh[kk & 3]);                       \
    bf16x8 al = __builtin_bit_cast(bf16x8, rl[kk & 3]);                       \
    if (kk + 4 < 16) {                                                        \
      const ull* ph_ = (QH) + ((size_t)(kk + 4) * 64 + lane) * 2;             \
      const ull* pl_ = (QL) + ((size_t)(kk + 4) * 64 + lane) * 2;             \
      rh[kk & 3].x = LOADA(ph_); rh[kk & 3].y = LOADA(ph_ + 1);               \
      rl[kk & 3].x = LOADA(pl_); rl[kk & 3].y = LOADA(pl_ + 1);               \
    }                                                                         \
    MFMA3(ah, al, (BHARR)[kk], (BLBASE) + ((kk * 64 + fq * 16) ^ xrB));       \
  } }

__global__ __launch_bounds__(256, 1)
void bilstm_v4(const float* __restrict__ inp, const int* __restrict__ lens,
               const float* __restrict__ Wf, const float* __restrict__ bfp,
               const float* __restrict__ Wb, const float* __restrict__ bbp,
               float* __restrict__ out, char* __restrict__ wsb) {
  extern __shared__ char lds[];
  const int tid = threadIdx.x, blk = blockIdx.x;
  const int group = blk >> 6, gslice = blk & 63;
  const int j0 = gslice * 8;
  const int dir = group >> 1, layer = group & 1;

  unsigned* flags = (unsigned*)(wsb + FLAG_OFF) + dir * 128;
  ull* hHq = (ull*)(wsb + HH_OFF) + (size_t)group * 2 * 4096;
  ull* hLq = (ull*)(wsb + HL_OFF) + (size_t)group * 2 * 4096;
  ull* rHq = (ull*)(wsb + RH_OFF) + (size_t)dir * 4 * 4096;
  ull* rLq = (ull*)(wsb + RL_OFF) + (size_t)dir * 4 * 4096;

  const float* Wg = (dir == 0 ? Wf : Wb) + (size_t)layer * 1024 * 2048;
  const float* bg = (dir == 0 ? bfp : bbp) + layer * 2048;

  // ---- init: W -> bf16 hi (LDS temp) / lo (LDS resident), RTN split ----
  for (int it = 0; it < 16; ++it) {
    int tt = tid + 256 * it;           // 4096 tasks = 1024 k x 4 gates
    int k = tt >> 2, gate = tt & 3;
    const float* src = Wg + (size_t)k * 2048 + gate * 512 + j0;
    float4 w0 = *(const float4*)src, w1 = *(const float4*)(src + 4);
    float wv[8] = {w0.x, w0.y, w0.z, w0.w, w1.x, w1.y, w1.z, w1.w};
#pragma unroll
    for (int u = 0; u < 8; ++u) {
      int c = u * 4 + gate;            // col = unit*4 + gate
      unsigned short hi, lo; split_f32(wv[u], hi, lo);
      int byte = c * 2048 + ((k * 2) ^ ((c & 7) << 4));
      *(unsigned short*)(lds + WHI_TMP + byte) = hi;
      *(unsigned short*)(lds + byte) = lo;
    }
  }
  __syncthreads();

  const int lane = tid & 63, wvid = tid >> 6;
  const int bt = wvid >> 1, ct = wvid & 1;       // wave tile (batch, col)
  const int fr = lane & 15, fq = lane >> 4;
  const int colN = ct * 16 + fr;
  const int xrB = (colN & 7) << 4;
  const char* BloX = lds + colN * 2048;          // B-lo, x half (k<512)
  const char* BloH = BloX + 1024;                // B-lo, h half

  // B-hi fragments -> registers (128 VGPR)
  bf16x8 bhX[16], bhH[16];
#pragma unroll
  for (int kk = 0; kk < 16; ++kk) {
    bhX[kk] = *(const bf16x8*)(lds + WHI_TMP + colN * 2048 + ((kk * 64 + fq * 16) ^ xrB));
    bhH[kk] = *(const bf16x8*)(lds + WHI_TMP + colN * 2048 + 1024 + ((kk * 64 + fq * 16) ^ xrB));
  }
  __syncthreads();   // WHI_TMP now free -> zb/staging

  float* zb = (float*)(lds + ZB_OFF);
  unsigned short* hs16 = (unsigned short*)(lds + HS_OFF);
  unsigned short* rs16 = (unsigned short*)(lds + RS_OFF);
  ull* hsq = (ull*)(lds + HS_OFF);
  ull* rsq = (ull*)(lds + RS_OFF);

  const int bi = tid >> 3, jj = tid & 7;         // pointwise mapping
  const int mylen = lens[bi];
  const int lenrow = lens[bt * 16 + fr];         // GEMM A-row length (bwd reversal)
  const float bias0 = bg[0 * 512 + j0 + jj];
  const float bias1 = bg[1 * 512 + j0 + jj];
  const float bias2 = bg[2 * 512 + j0 + jj];
  const float bias3 = bg[3 * 512 + j0 + jj];

  // fragment-store role (all computed once)
  const int role = tid >> 6, q = tid & 63;
  const int rg_s = q >> 5, lane_s = (q >> 1) & 15, u_s = q & 1;
  const int kk_blk = j0 >> 5, ksub = (j0 >> 3) & 3;
  const int gl = ((rg_s * 16 + kk_blk) * 64 + (ksub * 16 + lane_s)) * 2 + u_s;

  float c_reg = 0.f, h_reg = 0.f;

#pragma unroll 1
  for (int s = 0; s <= 1025; ++s) {
    const bool act = layer ? (s >= 2) : (s < 1024);
    const int t = layer ? (s - 2) : s;
    f32x4 acc0 = {0, 0, 0, 0}, acc1 = {0, 0, 0, 0}, acc2 = {0, 0, 0, 0};

    // ---- phase X: barrier-independent half (x from inp, or ring y0) ----
    if (act) {
      if (layer == 0) {
        int tr = t;
        if (dir == 1) tr = (t < lenrow) ? (lenrow - 1 - t) : t;
        const float* xp = inp + ((size_t)(bt * 16 + fr) * T_ + tr) * 512 + fq * 8;
#pragma unroll
        for (int kk = 0; kk < 16; ++kk) {
          float4 xa = *(const float4*)(xp + kk * 32);
          float4 xb = *(const float4*)(xp + kk * 32 + 4);
          unsigned h0 = packhi2(xa.x, xa.y), h1 = packhi2(xa.z, xa.w);
          unsigned h2 = packhi2(xb.x, xb.y), h3 = packhi2(xb.z, xb.w);
          unsigned l0 = packhi2(xa.x - hipart(xa.x), xa.y - hipart(xa.y));
          unsigned l1 = packhi2(xa.z - hipart(xa.z), xa.w - hipart(xa.w));
          unsigned l2 = packhi2(xb.x - hipart(xb.x), xb.y - hipart(xb.y));
          unsigned l3 = packhi2(xb.z - hipart(xb.z), xb.w - hipart(xb.w));
          u32x4 hv = {h0, h1, h2, h3}, lv = {l0, l1, l2, l3};
          bf16x8 ah = __builtin_bit_cast(bf16x8, hv);
          bf16x8 al = __builtin_bit_cast(bf16x8, lv);
          MFMA3(ah, al, bhX[kk], BloX + ((kk * 64 + fq * 16) ^ xrB));
        }
      } else {
        const ull* qh = rHq + (size_t)(t & 3) * 4096 + bt * 2048;
        const ull* ql = rLq + (size_t)(t & 3) * 4096 + bt * 2048;
        GEMM_FRAG(qh, ql, bhX, BloX);
      }
    }

    // ---- grid sync: wave 0 polls all 128 flags of this direction ----
    if (wvid == 0) {
      const unsigned tgt = (unsigned)s;
      while (true) {
        unsigned fa = LOADA(flags + lane);
        unsigned fb = LOADA(flags + lane + 64);
        if (__all((fa >= tgt) && (fb >= tgt))) break;
        __builtin_amdgcn_s_sleep(2);
      }
    }
    __syncthreads();
    asm volatile("" ::: "memory");

    // ---- phase H: recurrent half ----
    if (act) {
      const ull* qh = hHq + (size_t)(s & 1) * 4096 + bt * 2048;
      const ull* ql = hLq + (size_t)(s & 1) * 4096 + bt * 2048;
      GEMM_FRAG(qh, ql, bhH, BloH);
      f32x4 v = acc0 + acc1 + acc2;
#pragma unroll
      for (int r = 0; r < 4; ++r)
        zb[(bt * 16 + fq * 4 + r) * 33 + ct * 16 + fr] = v[r];
    }
    __syncthreads();

    // ---- pointwise LSTM cell ----
    if (act) {
      float z0 = zb[bi * 33 + jj * 4 + 0] + bias0;
      float z1 = zb[bi * 33 + jj * 4 + 1] + bias1;
      float z2 = zb[bi * 33 + jj * 4 + 2] + bias2;
      float z3 = zb[bi * 33 + jj * 4 + 3] + bias3;
      float ig = sigm(z0), fg = sigm(z2 + 1.0f), og = sigm(z3);
      float cn = fg * c_reg + ig * tanhf(z1);
      float hn = og * tanhf(cn);
      bool m = (t < mylen);
      if (m) { c_reg = cn; h_reg = hn; }
      unsigned short nh, nl; split_f32(h_reg, nh, nl);
      const int hsidx = (bi >> 4) * 128 + (bi & 15) * 8 + jj;
      hs16[hsidx] = nh; hs16[256 + hsidx] = nl;
      if (layer == 0) {
        float y = m ? hn : 0.f;
        unsigned short rh_, rl_; split_f32(y, rh_, rl_);
        rs16[hsidx] = rh_; rs16[256 + hsidx] = rl_;
      } else {
        int ot = t;
        if (dir == 1) ot = (t < mylen) ? (mylen - 1 - t) : t;
        out[((size_t)bi * T_ + ot) * 1024 + dir * 512 + j0 + jj] = m ? hn : 0.f;
      }
    }
    __syncthreads();

    // ---- publish h / ring as agent-scope atomic u64 (no fence needed) ----
    if (act) {
      if (role == 0)      STOREA(hHq + (size_t)((s + 1) & 1) * 4096 + gl, hsq[q]);
      else if (role == 1) STOREA(hLq + (size_t)((s + 1) & 1) * 4096 + gl, hsq[64 + q]);
      else if (layer == 0 && role == 2) STOREA(rHq + (size_t)(t & 3) * 4096 + gl, rsq[q]);
      else if (layer == 0 && role == 3) STOREA(rLq + (size_t)(t & 3) * 4096 + gl, rsq[64 + q]);
    }
    __syncthreads();   // per-wave vmcnt drain orders stores before flag
    asm volatile("" ::: "memory");
    if (tid == 0) STOREA(flags + layer * 64 + gslice, (unsigned)(s + 1));
  }
}

extern "C" void kernel_launch(void* const* d_in, const int* in_sizes, int n_in,
                              void* d_out, int out_size, void* d_ws, size_t ws_size,
                              hipStream_t stream) {
  const float* inp   = (const float*)d_in[0];
  const int*   lensp = (const int*)d_in[1];
  const float* Wf    = (const float*)d_in[2];
  const float* bfp   = (const float*)d_in[3];
  const float* Wb    = (const float*)d_in[4];
  const float* bbp   = (const float*)d_in[5];
  float*       outp  = (float*)d_out;
  char*        wsp   = (char*)d_ws;
  (void)in_sizes; (void)n_in; (void)out_size; (void)ws_size;

  hipMemsetAsync(d_ws, 0, WS_BYTES, stream);
  hipFuncSetAttribute((const void*)bilstm_v4,
                      hipFuncAttributeMaxDynamicSharedMemorySize, LDS_BYTES);
  bilstm_v4<<<dim3(256), dim3(256), LDS_BYTES, stream>>>(
      inp, lensp, Wf, bfp, Wb, bbp, outp, wsp);
}

// Round 5
// 7327.466 us; speedup vs baseline: 4.4165x; 1.4621x over previous
//
#include <hip/hip_runtime.h>
#include <stdint.h>

// ---------------------------------------------------------------------------
// BiLSTM encoder, persistent MFMA kernel (Round 5).
// vs R4: waves = (batch-half, k-quarter) -> zero-redundancy h/ring loads;
// h stored interleaved (hi<<16|lo) u32 fragment-major; ring single-bf16
// (8 slots); group-local flag polling (L0 decoupled from L1 jitter);
// direct per-thread u32 atomic publish (no LDS staging; 3 syncs/step);
// XCD-pair placement per group; full 8-frag prefetch; B-hi LDS region
// kept permanent (no reuse hazards).
// ---------------------------------------------------------------------------

#define B_ 32
#define T_ 1024
#define H_ 512

typedef __attribute__((ext_vector_type(8))) short bf16x8;
typedef __attribute__((ext_vector_type(4))) float f32x4;
typedef __attribute__((ext_vector_type(4))) unsigned int u32x4;
typedef unsigned long long ull;

// ws byte layout
#define FLAG_OFF  0                     // flags[2 dir][128] u32 (padded region)
#define H_OFF     4096                  // [4 grp][2 buf][2 bt][16 frag][64 lane][8 u32]
#define H_GRP_U64 (2 * 8192)            // u64 per group
#define R_OFF     (H_OFF + 4 * 2 * 65536)   // + 512KB
#define R_DIR_U64 (8 * 4096)            // [8 slot][2 bt][16 frag][64 lane][2 u64]
#define WS_BYTES  (R_OFF + 2 * 8 * 32768)   // + 512KB  => ~1.03 MB

// LDS byte layout
#define BLO_OFF   0                     // [32 col][1024 k] u16, pitch 2048, swz ((c&7)<<4)
#define BHI_OFF   65536                 // same geometry (permanent)
#define ZB0_OFF   131072                // f32[32][33]
#define ZB1_OFF   (ZB0_OFF + 4224)
#define LDS_BYTES (ZB1_OFF + 4224)      // 139520

#define LOADA(p)     __hip_atomic_load((p), __ATOMIC_RELAXED, __HIP_MEMORY_SCOPE_AGENT)
#define STOREA(p, v) __hip_atomic_store((p), (v), __ATOMIC_RELAXED, __HIP_MEMORY_SCOPE_AGENT)

__device__ __forceinline__ float sigm(float x) { return 1.f / (1.f + __expf(-x)); }
__device__ __forceinline__ unsigned short bf16_rtn(float f) {
  unsigned u = __builtin_bit_cast(unsigned, f);
  unsigned r = u + 0x7FFFu + ((u >> 16) & 1u);
  return (unsigned short)(r >> 16);
}
__device__ __forceinline__ float bf16f(unsigned short h) {
  return __builtin_bit_cast(float, (unsigned)h << 16);
}
__device__ __forceinline__ void split_f32(float f, unsigned short& hi, unsigned short& lo) {
  hi = bf16_rtn(f); lo = bf16_rtn(f - bf16f(hi));
}
// (bf16t(fa) low | bf16t(fb) high), truncating — proven in R4
__device__ __forceinline__ unsigned packhi2(float fa, float fb) {
  return __builtin_amdgcn_perm(__builtin_bit_cast(unsigned, fb),
                               __builtin_bit_cast(unsigned, fa), 0x07060302u);
}
__device__ __forceinline__ float hipart(float f) {
  return __builtin_bit_cast(float, __builtin_bit_cast(unsigned, f) & 0xFFFF0000u);
}
// from interleaved words w0=(hi0<<16|lo0), w1=(hi1<<16|lo1):
__device__ __forceinline__ unsigned hiPair(unsigned w0, unsigned w1) {
  return __builtin_amdgcn_perm(w1, w0, 0x07060302u);  // hi0 low | hi1 high
}
__device__ __forceinline__ unsigned loPair(unsigned w0, unsigned w1) {
  return __builtin_amdgcn_perm(w1, w0, 0x05040100u);  // lo0 low | lo1 high
}

#define MFMA(ACC, Af, Bf) ACC = __builtin_amdgcn_mfma_f32_16x16x32_bf16((Af), (Bf), (ACC), 0, 0, 0)

__global__ __launch_bounds__(256, 1)
void bilstm_v5(const float* __restrict__ inp, const int* __restrict__ lens,
               const float* __restrict__ Wf, const float* __restrict__ bfp,
               const float* __restrict__ Wb, const float* __restrict__ bbp,
               float* __restrict__ out, char* __restrict__ wsb) {
  extern __shared__ char lds[];
  const int tid = threadIdx.x, blk = blockIdx.x;
  // XCD-pair placement: assumes round-robin dispatch (perf heuristic only)
  const int xcd = blk & 7, slotp = blk >> 3;
  const int group = xcd >> 1;                 // 0..3 -> XCDs {2g,2g+1}
  const int gslice = (xcd & 1) * 32 + slotp;  // 0..63
  const int j0 = gslice * 8;
  const int dir = group >> 1, layer = group & 1;

  unsigned* flags = (unsigned*)(wsb + FLAG_OFF) + dir * 128;
  ull*      hgq   = (ull*)(wsb + H_OFF) + (size_t)group * H_GRP_U64;
  unsigned* hgw   = (unsigned*)hgq;
  ull*      rgq   = (ull*)(wsb + R_OFF) + (size_t)dir * R_DIR_U64;
  unsigned* rgw   = (unsigned*)rgq;

  const float* Wg = (dir == 0 ? Wf : Wb) + (size_t)layer * 1024 * 2048;
  const float* bg = (dir == 0 ? bfp : bbp) + layer * 2048;

  // ---- init: W -> bf16 hi (BHI) / lo (BLO), RTN split, swizzled ----
  for (int it = 0; it < 16; ++it) {
    int tt = tid + 256 * it;           // 4096 tasks = 1024 k x 4 gates
    int k = tt >> 2, gate = tt & 3;
    const float* src = Wg + (size_t)k * 2048 + gate * 512 + j0;
    float4 w0 = *(const float4*)src, w1 = *(const float4*)(src + 4);
    float wv[8] = {w0.x, w0.y, w0.z, w0.w, w1.x, w1.y, w1.z, w1.w};
#pragma unroll
    for (int u = 0; u < 8; ++u) {
      int c = u * 4 + gate;            // col = unit*4 + gate
      unsigned short hi, lo; split_f32(wv[u], hi, lo);
      int byte = c * 2048 + ((k * 2) ^ ((c & 7) << 4));
      *(unsigned short*)(lds + BHI_OFF + byte) = hi;
      *(unsigned short*)(lds + BLO_OFF + byte) = lo;
    }
  }
  __syncthreads();

  const int lane = tid & 63, wvid = tid >> 6;
  const int bt = wvid >> 1, kq = wvid & 1;       // batch-half, k-quarter
  const int fr = lane & 15, fq = lane >> 4;

  // B-hi fragments -> registers (this wave's k-quarter, both col-tiles)
  bf16x8 bhX[2][8], bhH[2][8];
  int colN[2], xr[2];
#pragma unroll
  for (int nt = 0; nt < 2; ++nt) {
    colN[nt] = nt * 16 + fr;
    xr[nt] = (colN[nt] & 7) << 4;
    const char* base = lds + BHI_OFF + colN[nt] * 2048;
#pragma unroll
    for (int kk = 0; kk < 8; ++kk) {
      int off = (kq * 512 + kk * 64 + fq * 16) ^ xr[nt];
      bhX[nt][kk] = *(const bf16x8*)(base + off);
      bhH[nt][kk] = *(const bf16x8*)(base + 1024 + off);
    }
  }

  float* zb0 = (float*)(lds + ZB0_OFF);
  float* zb1 = (float*)(lds + ZB1_OFF);
  float* zbme = kq ? zb1 : zb0;

  const int bi = tid >> 3, jj = tid & 7;         // pointwise mapping
  const int mylen = lens[bi];
  const int lenrow = lens[bt * 16 + fr];         // GEMM A-row length
  const float bias0 = bg[0 * 512 + j0 + jj];
  const float bias1 = bg[1 * 512 + j0 + jj];
  const float bias2 = bg[2 * 512 + j0 + jj];
  const float bias3 = bg[3 * 512 + j0 + jj];

  // publish-position constants (pointwise thread -> fragment-major u32 index)
  const int sbt = bi >> 4;                        // store-side batch half
  const int fragp = j0 >> 5;                      // frag of this block's units
  const int lanep = ((j0 >> 3) & 3) * 16 + (bi & 15);
  const int hpos = ((sbt * 16 + fragp) * 64 + lanep) * 8 + jj;   // u32 within buf
  const int rpos = ((sbt * 16 + fragp) * 64 + lanep) * 4 + (jj >> 1);

  float c_reg = 0.f, h_reg = 0.f;

#pragma unroll 1
  for (int s = 0; s <= 1025; ++s) {
    const bool act = layer ? (s >= 2) : (s < 1024);
    const int t = layer ? (s - 2) : s;
    f32x4 a00 = {0,0,0,0}, a01 = {0,0,0,0}, a02 = {0,0,0,0};
    f32x4 a10 = {0,0,0,0}, a11 = {0,0,0,0}, a12 = {0,0,0,0};

    // ---- phase X: barrier-independent half (x from inp, or ring y0) ----
    if (act) {
      if (layer == 0) {
        int tr = t;
        if (dir == 1) tr = (t < lenrow) ? (lenrow - 1 - t) : t;
        const float* xp = inp + ((size_t)(bt * 16 + fr) * T_ + tr) * 512 + kq * 256 + fq * 8;
#pragma unroll
        for (int kk = 0; kk < 8; ++kk) {
          float4 xa = *(const float4*)(xp + kk * 32);
          float4 xb = *(const float4*)(xp + kk * 32 + 4);
          unsigned h0 = packhi2(xa.x, xa.y), h1 = packhi2(xa.z, xa.w);
          unsigned h2 = packhi2(xb.x, xb.y), h3 = packhi2(xb.z, xb.w);
          unsigned l0 = packhi2(xa.x - hipart(xa.x), xa.y - hipart(xa.y));
          unsigned l1 = packhi2(xa.z - hipart(xa.z), xa.w - hipart(xa.w));
          unsigned l2 = packhi2(xb.x - hipart(xb.x), xb.y - hipart(xb.y));
          unsigned l3 = packhi2(xb.z - hipart(xb.z), xb.w - hipart(xb.w));
          u32x4 hv = {h0, h1, h2, h3}, lv = {l0, l1, l2, l3};
          bf16x8 ah = __builtin_bit_cast(bf16x8, hv);
          bf16x8 al = __builtin_bit_cast(bf16x8, lv);
          int ko = kq * 512 + kk * 64 + fq * 16;
          bf16x8 bl0 = *(const bf16x8*)(lds + BLO_OFF + colN[0] * 2048 + (ko ^ xr[0]));
          bf16x8 bl1 = *(const bf16x8*)(lds + BLO_OFF + colN[1] * 2048 + (ko ^ xr[1]));
          MFMA(a00, ah, bhX[0][kk]); MFMA(a01, ah, bl0); MFMA(a02, al, bhX[0][kk]);
          MFMA(a10, ah, bhX[1][kk]); MFMA(a11, ah, bl1); MFMA(a12, al, bhX[1][kk]);
        }
      } else {
        const ull* q = rgq + (size_t)(t & 7) * 4096 + bt * 2048 + kq * 1024 + lane * 2;
        ull rr[8][2];
#pragma unroll
        for (int kk = 0; kk < 8; ++kk) {
          rr[kk][0] = LOADA(q + kk * 128);
          rr[kk][1] = LOADA(q + kk * 128 + 1);
        }
#pragma unroll
        for (int kk = 0; kk < 8; ++kk) {
          bf16x8 ah = __builtin_bit_cast(bf16x8, rr[kk]);
          int ko = kq * 512 + kk * 64 + fq * 16;
          bf16x8 bl0 = *(const bf16x8*)(lds + BLO_OFF + colN[0] * 2048 + (ko ^ xr[0]));
          bf16x8 bl1 = *(const bf16x8*)(lds + BLO_OFF + colN[1] * 2048 + (ko ^ xr[1]));
          MFMA(a00, ah, bhX[0][kk]); MFMA(a01, ah, bl0);
          MFMA(a10, ah, bhX[1][kk]); MFMA(a11, ah, bl1);
        }
      }
    }

    // ---- grid sync: wave 0 polls own group's 64 flags (+ cross-layer dep) ----
    if (wvid == 0) {
      const int tgt_own = s;
      const int tgt_oth = layer ? s : (s - 5);   // L1 ring-avail / L0 anti-overrun
      while (true) {
        int fa = (int)LOADA(flags + layer * 64 + lane);
        int fb = (int)LOADA(flags + (1 - layer) * 64 + lane);
        if (__all((fa >= tgt_own) && (fb >= tgt_oth))) break;
        __builtin_amdgcn_s_sleep(1);
      }
    }
    __syncthreads();
    asm volatile("" ::: "memory");

    // ---- phase H: recurrent half (full prefetch, interleaved unpack) ----
    if (act) {
      const ull* q = hgq + (size_t)(s & 1) * 8192 + bt * 4096 + kq * 2048 + lane * 4;
      ull ra[8][4];
#pragma unroll
      for (int kk = 0; kk < 8; ++kk) {
#pragma unroll
        for (int w = 0; w < 4; ++w) ra[kk][w] = LOADA(q + kk * 256 + w);
      }
#pragma unroll
      for (int kk = 0; kk < 8; ++kk) {
        unsigned w0 = (unsigned)ra[kk][0], w1 = (unsigned)(ra[kk][0] >> 32);
        unsigned w2 = (unsigned)ra[kk][1], w3 = (unsigned)(ra[kk][1] >> 32);
        unsigned w4 = (unsigned)ra[kk][2], w5 = (unsigned)(ra[kk][2] >> 32);
        unsigned w6 = (unsigned)ra[kk][3], w7 = (unsigned)(ra[kk][3] >> 32);
        u32x4 hv = {hiPair(w0, w1), hiPair(w2, w3), hiPair(w4, w5), hiPair(w6, w7)};
        u32x4 lv = {loPair(w0, w1), loPair(w2, w3), loPair(w4, w5), loPair(w6, w7)};
        bf16x8 ah = __builtin_bit_cast(bf16x8, hv);
        bf16x8 al = __builtin_bit_cast(bf16x8, lv);
        int ko = 1024 + kq * 512 + kk * 64 + fq * 16;
        bf16x8 bl0 = *(const bf16x8*)(lds + BLO_OFF + colN[0] * 2048 + (ko ^ xr[0]));
        bf16x8 bl1 = *(const bf16x8*)(lds + BLO_OFF + colN[1] * 2048 + (ko ^ xr[1]));
        MFMA(a00, ah, bhH[0][kk]); MFMA(a01, ah, bl0); MFMA(a02, al, bhH[0][kk]);
        MFMA(a10, ah, bhH[1][kk]); MFMA(a11, ah, bl1); MFMA(a12, al, bhH[1][kk]);
      }
      f32x4 v0 = a00 + a01 + a02, v1 = a10 + a11 + a12;
#pragma unroll
      for (int r = 0; r < 4; ++r) {
        zbme[(bt * 16 + fq * 4 + r) * 33 + fr] = v0[r];
        zbme[(bt * 16 + fq * 4 + r) * 33 + 16 + fr] = v1[r];
      }
    }
    __syncthreads();

    // ---- pointwise LSTM cell + direct atomic publish ----
    if (act) {
      const int zo = bi * 33 + jj * 4;
      float z0 = zb0[zo + 0] + zb1[zo + 0] + bias0;
      float z1 = zb0[zo + 1] + zb1[zo + 1] + bias1;
      float z2 = zb0[zo + 2] + zb1[zo + 2] + bias2;
      float z3 = zb0[zo + 3] + zb1[zo + 3] + bias3;
      float ig = sigm(z0), fg = sigm(z2 + 1.0f), og = sigm(z3);
      float cn = fg * c_reg + ig * tanhf(z1);
      float hn = og * tanhf(cn);
      const bool m = (t < mylen);
      if (m) { c_reg = cn; h_reg = hn; }
      unsigned short nh, nl; split_f32(h_reg, nh, nl);
      unsigned word = ((unsigned)nh << 16) | nl;
      STOREA(hgw + (size_t)((s + 1) & 1) * 16384 + hpos, word);
      if (layer == 0) {
        float y = m ? hn : 0.f;
        unsigned ry = bf16_rtn(y);
        unsigned nb = __shfl_down((int)ry, 1);
        if ((jj & 1) == 0)
          STOREA(rgw + (size_t)(t & 7) * 8192 + rpos, ry | (nb << 16));
      } else {
        int ot = t;
        if (dir == 1) ot = (t < mylen) ? (mylen - 1 - t) : t;
        out[((size_t)bi * T_ + ot) * 1024 + dir * 512 + j0 + jj] = m ? hn : 0.f;
      }
    }
    __syncthreads();   // barrier drains each wave's stores before flag
    if (tid == 0) STOREA(flags + layer * 64 + gslice, (unsigned)(s + 1));
  }
}

extern "C" void kernel_launch(void* const* d_in, const int* in_sizes, int n_in,
                              void* d_out, int out_size, void* d_ws, size_t ws_size,
                              hipStream_t stream) {
  const float* inp   = (const float*)d_in[0];
  const int*   lensp = (const int*)d_in[1];
  const float* Wf    = (const float*)d_in[2];
  const float* bfp   = (const float*)d_in[3];
  const float* Wb    = (const float*)d_in[4];
  const float* bbp   = (const float*)d_in[5];
  float*       outp  = (float*)d_out;
  char*        wsp   = (char*)d_ws;
  (void)in_sizes; (void)n_in; (void)out_size; (void)ws_size;

  hipMemsetAsync(d_ws, 0, WS_BYTES, stream);
  hipFuncSetAttribute((const void*)bilstm_v5,
                      hipFuncAttributeMaxDynamicSharedMemorySize, LDS_BYTES);
  bilstm_v5<<<dim3(256), dim3(256), LDS_BYTES, stream>>>(
      inp, lensp, Wf, bfp, Wb, bbp, outp, wsp);
}